// Round 6
// baseline (318.304 us; speedup 1.0000x reference)
//
#include <hip/hip_runtime.h>
#include <hip/hip_bf16.h>
#include <math.h>

typedef __attribute__((ext_vector_type(8))) short bf16x8;
typedef __attribute__((ext_vector_type(4))) float f32x4;
typedef unsigned short u16;
typedef __hip_bfloat16 HB;

#define B_ 4
#define S_ 2048
#define D_ 1024
#define H_ 16
#define HD_ 64

__device__ __forceinline__ u16 f2b(float f) {
  HB h = __float2bfloat16(f);
  return *reinterpret_cast<u16*>(&h);
}
__device__ __forceinline__ void store1(HB* p, float v) { *p = __float2bfloat16(v); }
__device__ __forceinline__ void store1(float* p, float v) { *p = v; }

__device__ __forceinline__ float fexp2(float x) {
#if __has_builtin(__builtin_amdgcn_exp2f)
  return __builtin_amdgcn_exp2f(x);
#else
  return exp2f(x);
#endif
}

// async 16B global->LDS DMA. LDS dest semantics: wave-uniform base + lane*16
// (m104): pass the SAME base for all lanes of a wave; lane i lands at +16*i.
__device__ __forceinline__ void glds16(const u16* g, u16* l) {
  __builtin_amdgcn_global_load_lds(
      (const __attribute__((address_space(1))) void*)g,
      (__attribute__((address_space(3))) void*)l, 16, 0, 0);
}

// ---------------- cast x (fp32) -> bf16 --------------------------------------
__global__ __launch_bounds__(256) void cast_x(const float* __restrict__ xin,
                                              u16* __restrict__ xout) {
  const long i0 = ((long)blockIdx.x * 256 + threadIdx.x) * 8;
  bf16x8 r;
#pragma unroll
  for (int j = 0; j < 8; ++j) r[j] = (short)f2b(xin[i0 + j]);
  *(bf16x8*)(xout + i0) = r;
}

// ---------------- Weight transpose: Wt[n][k] = bf16(W[k][n]), 1024x1024 ------
__global__ __launch_bounds__(256) void transpose_w(
    const float* __restrict__ w0, const float* __restrict__ w1,
    const float* __restrict__ w2, const float* __restrict__ w3,
    u16* __restrict__ out) {
  __shared__ __align__(16) u16 T[64 * 72];
  const float* Ws[4] = {w0, w1, w2, w3};
  const float* W = Ws[blockIdx.z];
  u16* Wt = out + (long)blockIdx.z * (1 << 20);
  const int t = threadIdx.x;
  const int r = t >> 3;            // 0..31
  const int c8 = (t & 7) * 8;      // 0..56
#pragma unroll
  for (int it = 0; it < 2; ++it) {
    const int row = blockIdx.y * 64 + it * 32 + r;           // W row (k)
    const float* src = W + (long)row * D_ + blockIdx.x * 64 + c8;
#pragma unroll
    for (int j = 0; j < 8; ++j) T[(c8 + j) * 72 + it * 32 + r] = f2b(src[j]);
  }
  __syncthreads();
#pragma unroll
  for (int it = 0; it < 2; ++it) {
    const int row = it * 32 + r;                             // Wt local row (n)
    bf16x8 v = *(const bf16x8*)(&T[row * 72 + c8]);
    *(bf16x8*)(Wt + (long)(blockIdx.x * 64 + row) * D_ + blockIdx.y * 64 + c8) = v;
  }
}

// ---------------- GEMM v2: double-buffered BK=64 pipeline --------------------
// 128x128 tile, BK=64, LDS 64KB (2 blocks/CU). Per K-tile: issue next tile's
// 8 global_load_lds FIRST, then ds_read + 32 MFMA on current buffer, then one
// __syncthreads (drains vmcnt -> next tile landed; readers of current done).
// 64-wide LDS rows, XOR chunk swizzle: LDS slot s of row r holds global
// chunk s ^ (r&7); frag read chunk c at slot c ^ (m&7) -> 2-way alias (free).
// Grid flattened + bijective XCD swizzle (nwg % 8 == 0 by construction).
template <typename OT>
__global__ __launch_bounds__(256) void gemm_bt128d(
    const u16* __restrict__ A, const u16* __restrict__ BTb, long bt_stride,
    OT* __restrict__ Cb, long c_stride, const float* __restrict__ bias,
    u16* __restrict__ vt, int scale_q, int M, int N, int K) {
  // ---- XCD swizzle over flat grid; gx=8, gy=64 hardcoded (nxy=512) ----
  const int flat = ((int)blockIdx.z << 9) + ((int)blockIdx.y << 3) + blockIdx.x;
  const int cpx = ((int)gridDim.z << 9) >> 3;  // nwg / 8
  const int nf = (flat & 7) * cpx + (flat >> 3);
  const int bz = nf >> 9;
  const int rem = nf & 511;
  const int by = rem >> 3, bx = rem & 7;

  const u16* BT = BTb + (long)bz * bt_stride;
  OT* C = Cb + (long)bz * c_stride;

  __shared__ __align__(16) u16 As[2][128 * 64];
  __shared__ __align__(16) u16 Bs[2][128 * 64];

  const int tid = threadIdx.x;
  const int w = tid >> 6, lane = tid & 63;
  const int qr = lane & 15, quad = lane >> 4;
  const int wm = w >> 1, wn = w & 1;

  const long rowA0 = (long)by * 128;
  const long rowB0 = (long)bx * 128;

  // staging map: issue t covers rows w*32 + t*8 .. +7; lane -> +(lane>>3),
  // LDS chunk slot lane&7 holds global chunk (lane&7)^(lane>>3)
  const int sr8 = lane >> 3;
  const int sc8 = ((lane & 7) ^ sr8) * 8;

  f32x4 acc[4][4] = {};

#define STAGE(nb, k0)                                                      \
  {                                                                        \
    _Pragma("unroll") for (int t = 0; t < 4; ++t) {                        \
      const int r = w * 32 + t * 8;                                        \
      glds16(A + (rowA0 + r + sr8) * K + (k0) + sc8, &As[nb][r * 64]);     \
      glds16(BT + (rowB0 + r + sr8) * K + (k0) + sc8, &Bs[nb][r * 64]);    \
    }                                                                      \
  }

  STAGE(0, 0);
  __syncthreads();  // drains vmcnt: tile 0 visible

  const int NT = K >> 6;
  for (int kt = 0; kt < NT; ++kt) {
    const int b = kt & 1;
    if (kt + 1 < NT) STAGE(b ^ 1, (kt + 1) << 6);  // prefetch, stays in flight

#pragma unroll
    for (int kk = 0; kk < 2; ++kk) {
      bf16x8 af[4], bf[4];
#pragma unroll
      for (int ms = 0; ms < 4; ++ms) {
        const int m = wm * 64 + ms * 16 + qr;
        af[ms] = *(const bf16x8*)(&As[b][m * 64 +
                                         (((kk * 4 + quad) ^ (m & 7)) * 8)]);
      }
#pragma unroll
      for (int ns = 0; ns < 4; ++ns) {
        const int n = wn * 64 + ns * 16 + qr;
        bf[ns] = *(const bf16x8*)(&Bs[b][n * 64 +
                                         (((kk * 4 + quad) ^ (n & 7)) * 8)]);
      }
#pragma unroll
      for (int ms = 0; ms < 4; ++ms)
#pragma unroll
        for (int ns = 0; ns < 4; ++ns)
          acc[ms][ns] = __builtin_amdgcn_mfma_f32_16x16x32_bf16(
              af[ms], bf[ns], acc[ms][ns], 0, 0, 0);
    }
    __syncthreads();  // drains vmcnt (tile kt+1 landed); readers of buf b done
  }
#undef STAGE

  if (vt && bz == 2) {
    // transposed V write: Vt[(b*H + h)*HD + hd][s]
#pragma unroll
    for (int ns = 0; ns < 4; ++ns) {
      const int col = (int)rowB0 + wn * 64 + ns * 16 + qr;   // h*64 + hd
#pragma unroll
      for (int ms = 0; ms < 4; ++ms) {
        const long row = rowA0 + wm * 64 + ms * 16 + quad * 4;  // b*2048 + s
        const long b = row >> 11, s = row & 2047;
        ushort4 pk;
        pk.x = f2b(acc[ms][ns][0]); pk.y = f2b(acc[ms][ns][1]);
        pk.z = f2b(acc[ms][ns][2]); pk.w = f2b(acc[ms][ns][3]);
        *(ushort4*)(vt + ((b * H_ + (col >> 6)) * HD_ + (col & 63)) * S_ + s) = pk;
      }
    }
    return;
  }

  // Q pre-scale folds 1/sqrt(HD) AND log2(e): attention uses exp2 directly.
  const float qs = (scale_q && bz == 0) ? 0.18033688011112042f : 1.f;
#pragma unroll
  for (int ns = 0; ns < 4; ++ns) {
    const long col = rowB0 + wn * 64 + ns * 16 + qr;
    const float bv = bias ? bias[col] : 0.f;
#pragma unroll
    for (int ms = 0; ms < 4; ++ms) {
      const long row = rowA0 + wm * 64 + ms * 16 + quad * 4;
#pragma unroll
      for (int r = 0; r < 4; ++r)
        store1(&C[(row + r) * (long)N + col], acc[ms][ns][r] * qs + bv);
    }
  }
}

// ---------------- Causal flash attention v9: LDS-free K/V --------------------
// DS pipe was the saturated resource (kf/vf = same 16KB K/V tile pulled
// through ds_read_b128 by ALL 4 waves). K ([s][d]) and V^T ([hd][s]) global
// layouts are directly MFMA-fragment-coalesced (16B/lane, full 64B lines),
// so fragments load global->VGPR: the 4x duplication is served by the idle
// per-CU L1 (4 waves share a tile -> 1 L2 miss + 3 L1 hits), L2 sees each
// tile once (XCD swizzle: all 16 q-blocks of a bh on one XCD; 8 bh x 512KB
// = its 4MB L2). No staging, no double-buffer, NO barriers -> waves free-run;
// LDS = 8KB P slab only. Grid (64,16) LPT (y->qp=15-y), 1024 blocks.
// Softmax denominator via ones-MFMA: li_acc[i] = mfma(pf, ones, li_acc) has
// the SAME D-fragment layout as o -> kills 16 adds + 2 shfl per tile and the
// epilogue shfl; runs on the underused MFMA pipe.
// Swapped QK^T: lane holds a full q-row's 16 P-values (k=16ns+4quad+r).
// Q pre-scaled by log2e/8 -> raw v_exp_f32 (exp2).
__global__ __launch_bounds__(256) void attn9(
    const u16* __restrict__ Q, const u16* __restrict__ Kg,
    const u16* __restrict__ Vt, u16* __restrict__ ctx) {
  __shared__ __align__(16) u16 Pl[4][16 * 64];  // [wave][q-row * 64k], XOR-swz

  const int tid = threadIdx.x;
  const int w = tid >> 6, lane = tid & 63;
  const int qr = lane & 15, quad = lane >> 4;
  const int bh = blockIdx.x;
  const int b = bh >> 4, h = bh & 15;

  const long baseQK = ((long)b * S_) * D_ + h * HD_;
  const long baseVt = (long)bh * HD_ * S_;

  const int qp = 15 - (int)blockIdx.y;  // LPT: longest blocks dispatch first
  const int q0 = qp * 128;
  const int qbase = q0 + w * 32;

  bf16x8 aq[2][2];
#pragma unroll
  for (int i = 0; i < 2; ++i) {
    const u16* qp_ = Q + baseQK + (long)(qbase + i * 16 + qr) * D_;
    aq[i][0] = *(const bf16x8*)(qp_ + quad * 8);
    aq[i][1] = *(const bf16x8*)(qp_ + 32 + quad * 8);
  }

  bf16x8 vones;
#pragma unroll
  for (int j = 0; j < 8; ++j) vones[j] = (short)0x3F80;  // bf16 1.0

  f32x4 li[2] = {};   // ones-MFMA accumulator: entry r = rowsum(q=quad*4+r)
  f32x4 o[2][4] = {};

  const int nkt = q0 / 64 + 2;  // covers k <= q0+127

  for (int kt = 0; kt < nkt; ++kt) {
    const int kbase = kt * 64;
    const u16* Kt = Kg + baseQK + (long)kbase * D_;
    const u16* Vp = Vt + baseVt + kbase;

    // K fragments straight from global (L1/L2-served, coalesced 16B/lane)
    bf16x8 kf[4][2];
#pragma unroll
    for (int ns = 0; ns < 4; ++ns) {
      const u16* kr = Kt + (long)(ns * 16 + qr) * D_ + quad * 8;
      kf[ns][0] = *(const bf16x8*)(kr);
      kf[ns][1] = *(const bf16x8*)(kr + 32);
    }

    // S^T = K * Q^T: lane holds q = qbase+i*16+qr, k = kbase+ns*16+quad*4+r
    f32x4 s[2][4] = {};
#pragma unroll
    for (int i = 0; i < 2; ++i)
#pragma unroll
      for (int ns = 0; ns < 4; ++ns) {
        s[i][ns] = __builtin_amdgcn_mfma_f32_16x16x32_bf16(
            kf[ns][0], aq[i][0], s[i][ns], 0, 0, 0);
        s[i][ns] = __builtin_amdgcn_mfma_f32_16x16x32_bf16(
            kf[ns][1], aq[i][1], s[i][ns], 0, 0, 0);
      }

    // V fragments straight from global (issued here; land during softmax)
    bf16x8 vf[4][2];
#pragma unroll
    for (int ns = 0; ns < 4; ++ns) {
      const u16* vr = Vp + (long)(ns * 16 + qr) * S_ + quad * 8;
      vf[ns][0] = *(const bf16x8*)(vr);
      vf[ns][1] = *(const bf16x8*)(vr + 32);
    }

    // causal mask (wave-uniform gate per m-frag)
#pragma unroll
    for (int i = 0; i < 2; ++i) {
      if (kbase + 64 > qbase + i * 16) {
        const int qrow = qbase + i * 16 + qr;
#pragma unroll
        for (int ns = 0; ns < 4; ++ns) {
          const int kc = kbase + ns * 16 + quad * 4;
#pragma unroll
          for (int r = 0; r < 4; ++r)
            if (kc + r > qrow) s[i][ns][r] = -1.0e30f;
        }
      }
    }

    // fixed-max softmax per-lane + slim P slab (wave-private, in-order DS).
    // P[q][k]: 16B chunk k/8 stored at chunk ^ (q&7) within the row.
#pragma unroll
    for (int i = 0; i < 2; ++i) {
#pragma unroll
      for (int ns = 0; ns < 4; ++ns) {
        ushort4 pk;
        pk.x = f2b(fexp2(s[i][ns][0]));
        pk.y = f2b(fexp2(s[i][ns][1]));
        pk.z = f2b(fexp2(s[i][ns][2]));
        pk.w = f2b(fexp2(s[i][ns][3]));
        *(ushort4*)(&Pl[w][qr * 64 +
                           (((2 * ns + (quad >> 1)) ^ (qr & 7)) * 8) +
                           (quad & 1) * 4]) = pk;
      }

      bf16x8 pf0 = *(const bf16x8*)(&Pl[w][qr * 64 + ((quad ^ (qr & 7)) * 8)]);
      bf16x8 pf1 =
          *(const bf16x8*)(&Pl[w][qr * 64 + (((4 + quad) ^ (qr & 7)) * 8)]);
#pragma unroll
      for (int ns = 0; ns < 4; ++ns) {
        o[i][ns] = __builtin_amdgcn_mfma_f32_16x16x32_bf16(pf0, vf[ns][0],
                                                           o[i][ns], 0, 0, 0);
        o[i][ns] = __builtin_amdgcn_mfma_f32_16x16x32_bf16(pf1, vf[ns][1],
                                                           o[i][ns], 0, 0, 0);
      }
      // denominator on the MFMA pipe; D-frag layout matches o
      li[i] = __builtin_amdgcn_mfma_f32_16x16x32_bf16(pf0, vones, li[i], 0, 0, 0);
      li[i] = __builtin_amdgcn_mfma_f32_16x16x32_bf16(pf1, vones, li[i], 0, 0, 0);
    }
  }

  // epilogue: li[i][r] is the rowsum for q = qbase+i*16+quad*4+r (no shfl)
#pragma unroll
  for (int i = 0; i < 2; ++i)
#pragma unroll
    for (int r = 0; r < 4; ++r) {
      const float inv = 1.f / li[i][r];
      const long row = qbase + i * 16 + quad * 4 + r;
#pragma unroll
      for (int ns = 0; ns < 4; ++ns)
        ctx[((long)b * S_ + row) * D_ + h * HD_ + ns * 16 + qr] =
            f2b(o[i][ns][r] * inv);
    }
}

// ---------------- launch ------------------------------------------------------
extern "C" void kernel_launch(void* const* d_in, const int* in_sizes, int n_in,
                              void* d_out, int out_size, void* d_ws,
                              size_t ws_size, hipStream_t stream) {
  const float* x  = (const float*)d_in[0];
  const float* Wq = (const float*)d_in[1];
  const float* Wk = (const float*)d_in[2];
  const float* Wv = (const float*)d_in[3];
  const float* Wo = (const float*)d_in[4];
  const float* bo = (const float*)d_in[5];

  u16* ws = (u16*)d_ws;
  u16* xb  = ws;                         // 8.4M elems bf16 x
  u16* Wt  = xb + 8388608l;              // 4 * 1M elems (transposed bf16 W)
  u16* Qb  = Wt + 4l * 1048576;          // Q (pre-scaled), [B,S,H*HD]
  u16* Kb  = Qb + 8388608l;              // K, [B,S,H*HD]
  u16* Vb  = Kb + 8388608l;              // V^T, [B*H, HD, S]
  u16* ctx = Qb;  // alias: q-tiles are block-exclusive; Q rows are read
                  // before the same rows are written

  // 1) x -> bf16
  cast_x<<<4096, 256, 0, stream>>>(x, xb);

  // 2) transpose+convert the 4 weight matrices
  transpose_w<<<dim3(16, 16, 4), 256, 0, stream>>>(Wq, Wk, Wv, Wo, Wt);

  // 3) QKV projections: Q scaled by log2e/8, V written transposed
  gemm_bt128d<HB><<<dim3(8, 64, 3), 256, 0, stream>>>(
      xb, Wt, 1048576l, (HB*)Qb, 8388608l, nullptr, Vb, 1, 8192, 1024, 1024);

  // 4) causal flash attention -> ctx
  attn9<<<dim3(64, 16), 256, 0, stream>>>(Qb, Kb, Vb, ctx);

  // 5) output projection + bias -> d_out (fp32)
  gemm_bt128d<float><<<dim3(8, 64, 1), 256, 0, stream>>>(
      ctx, Wt + 3l * 1048576, 0, (float*)d_out, 0, bo, nullptr, 0,
      8192, 1024, 1024);
}

// Round 9
// 246.582 us; speedup vs baseline: 1.2909x; 1.2909x over previous
//
#include <hip/hip_runtime.h>
#include <hip/hip_bf16.h>
#include <math.h>

typedef __attribute__((ext_vector_type(8))) short bf16x8;
typedef __attribute__((ext_vector_type(4))) float f32x4;
typedef unsigned short u16;
typedef __hip_bfloat16 HB;

#define B_ 4
#define S_ 2048
#define D_ 1024
#define H_ 16
#define HD_ 64

__device__ __forceinline__ u16 f2b(float f) {
  HB h = __float2bfloat16(f);
  return *reinterpret_cast<u16*>(&h);
}
__device__ __forceinline__ void store1(HB* p, float v) { *p = __float2bfloat16(v); }
__device__ __forceinline__ void store1(float* p, float v) { *p = v; }

__device__ __forceinline__ float fexp2(float x) {
#if __has_builtin(__builtin_amdgcn_exp2f)
  return __builtin_amdgcn_exp2f(x);
#else
  return exp2f(x);
#endif
}

// async 16B global->LDS DMA. LDS dest semantics: wave-uniform base + lane*16
// (m104): pass the SAME base for all lanes of a wave; lane i lands at +16*i.
__device__ __forceinline__ void glds16(const u16* g, u16* l) {
  __builtin_amdgcn_global_load_lds(
      (const __attribute__((address_space(1))) void*)g,
      (__attribute__((address_space(3))) void*)l, 16, 0, 0);
}

// ---------------- cast x (fp32) -> bf16 --------------------------------------
__global__ __launch_bounds__(256) void cast_x(const float* __restrict__ xin,
                                              u16* __restrict__ xout) {
  const long i0 = ((long)blockIdx.x * 256 + threadIdx.x) * 8;
  bf16x8 r;
#pragma unroll
  for (int j = 0; j < 8; ++j) r[j] = (short)f2b(xin[i0 + j]);
  *(bf16x8*)(xout + i0) = r;
}

// ---------------- Weight transpose: Wt[n][k] = bf16(W[k][n]), 1024x1024 ------
__global__ __launch_bounds__(256) void transpose_w(
    const float* __restrict__ w0, const float* __restrict__ w1,
    const float* __restrict__ w2, const float* __restrict__ w3,
    u16* __restrict__ out) {
  __shared__ __align__(16) u16 T[64 * 72];
  const float* Ws[4] = {w0, w1, w2, w3};
  const float* W = Ws[blockIdx.z];
  u16* Wt = out + (long)blockIdx.z * (1 << 20);
  const int t = threadIdx.x;
  const int r = t >> 3;            // 0..31
  const int c8 = (t & 7) * 8;      // 0..56
#pragma unroll
  for (int it = 0; it < 2; ++it) {
    const int row = blockIdx.y * 64 + it * 32 + r;           // W row (k)
    const float* src = W + (long)row * D_ + blockIdx.x * 64 + c8;
#pragma unroll
    for (int j = 0; j < 8; ++j) T[(c8 + j) * 72 + it * 32 + r] = f2b(src[j]);
  }
  __syncthreads();
#pragma unroll
  for (int it = 0; it < 2; ++it) {
    const int row = it * 32 + r;                             // Wt local row (n)
    bf16x8 v = *(const bf16x8*)(&T[row * 72 + c8]);
    *(bf16x8*)(Wt + (long)(blockIdx.x * 64 + row) * D_ + blockIdx.y * 64 + c8) = v;
  }
}

// ---------------- GEMM v2: double-buffered BK=64 pipeline --------------------
// 128x128 tile, BK=64, LDS 64KB (2 blocks/CU). Per K-tile: issue next tile's
// 8 global_load_lds FIRST, then ds_read + 32 MFMA on current buffer, then one
// __syncthreads (drains vmcnt -> next tile landed; readers of current done).
// 64-wide LDS rows, XOR chunk swizzle: LDS slot s of row r holds global
// chunk s ^ (r&7); frag read chunk c at slot c ^ (m&7) -> 2-way alias (free).
// Grid flattened + bijective XCD swizzle (nwg % 8 == 0 by construction).
template <typename OT>
__global__ __launch_bounds__(256) void gemm_bt128d(
    const u16* __restrict__ A, const u16* __restrict__ BTb, long bt_stride,
    OT* __restrict__ Cb, long c_stride, const float* __restrict__ bias,
    u16* __restrict__ vt, int scale_q, int M, int N, int K) {
  // ---- XCD swizzle over flat grid; gx=8, gy=64 hardcoded (nxy=512) ----
  const int flat = ((int)blockIdx.z << 9) + ((int)blockIdx.y << 3) + blockIdx.x;
  const int cpx = ((int)gridDim.z << 9) >> 3;  // nwg / 8
  const int nf = (flat & 7) * cpx + (flat >> 3);
  const int bz = nf >> 9;
  const int rem = nf & 511;
  const int by = rem >> 3, bx = rem & 7;

  const u16* BT = BTb + (long)bz * bt_stride;
  OT* C = Cb + (long)bz * c_stride;

  __shared__ __align__(16) u16 As[2][128 * 64];
  __shared__ __align__(16) u16 Bs[2][128 * 64];

  const int tid = threadIdx.x;
  const int w = tid >> 6, lane = tid & 63;
  const int qr = lane & 15, quad = lane >> 4;
  const int wm = w >> 1, wn = w & 1;

  const long rowA0 = (long)by * 128;
  const long rowB0 = (long)bx * 128;

  // staging map: issue t covers rows w*32 + t*8 .. +7; lane -> +(lane>>3),
  // LDS chunk slot lane&7 holds global chunk (lane&7)^(lane>>3)
  const int sr8 = lane >> 3;
  const int sc8 = ((lane & 7) ^ sr8) * 8;

  f32x4 acc[4][4] = {};

#define STAGE(nb, k0)                                                      \
  {                                                                        \
    _Pragma("unroll") for (int t = 0; t < 4; ++t) {                        \
      const int r = w * 32 + t * 8;                                        \
      glds16(A + (rowA0 + r + sr8) * K + (k0) + sc8, &As[nb][r * 64]);     \
      glds16(BT + (rowB0 + r + sr8) * K + (k0) + sc8, &Bs[nb][r * 64]);    \
    }                                                                      \
  }

  STAGE(0, 0);
  __syncthreads();  // drains vmcnt: tile 0 visible

  const int NT = K >> 6;
  for (int kt = 0; kt < NT; ++kt) {
    const int b = kt & 1;
    if (kt + 1 < NT) STAGE(b ^ 1, (kt + 1) << 6);  // prefetch, stays in flight

#pragma unroll
    for (int kk = 0; kk < 2; ++kk) {
      bf16x8 af[4], bf[4];
#pragma unroll
      for (int ms = 0; ms < 4; ++ms) {
        const int m = wm * 64 + ms * 16 + qr;
        af[ms] = *(const bf16x8*)(&As[b][m * 64 +
                                         (((kk * 4 + quad) ^ (m & 7)) * 8)]);
      }
#pragma unroll
      for (int ns = 0; ns < 4; ++ns) {
        const int n = wn * 64 + ns * 16 + qr;
        bf[ns] = *(const bf16x8*)(&Bs[b][n * 64 +
                                         (((kk * 4 + quad) ^ (n & 7)) * 8)]);
      }
#pragma unroll
      for (int ms = 0; ms < 4; ++ms)
#pragma unroll
        for (int ns = 0; ns < 4; ++ns)
          acc[ms][ns] = __builtin_amdgcn_mfma_f32_16x16x32_bf16(
              af[ms], bf[ns], acc[ms][ns], 0, 0, 0);
    }
    __syncthreads();  // drains vmcnt (tile kt+1 landed); readers of buf b done
  }
#undef STAGE

  if (vt && bz == 2) {
    // transposed V write: Vt[(b*H + h)*HD + hd][s]
#pragma unroll
    for (int ns = 0; ns < 4; ++ns) {
      const int col = (int)rowB0 + wn * 64 + ns * 16 + qr;   // h*64 + hd
#pragma unroll
      for (int ms = 0; ms < 4; ++ms) {
        const long row = rowA0 + wm * 64 + ms * 16 + quad * 4;  // b*2048 + s
        const long b = row >> 11, s = row & 2047;
        ushort4 pk;
        pk.x = f2b(acc[ms][ns][0]); pk.y = f2b(acc[ms][ns][1]);
        pk.z = f2b(acc[ms][ns][2]); pk.w = f2b(acc[ms][ns][3]);
        *(ushort4*)(vt + ((b * H_ + (col >> 6)) * HD_ + (col & 63)) * S_ + s) = pk;
      }
    }
    return;
  }

  // Q pre-scale folds 1/sqrt(HD) AND log2(e): attention uses exp2 directly.
  const float qs = (scale_q && bz == 0) ? 0.18033688011112042f : 1.f;
#pragma unroll
  for (int ns = 0; ns < 4; ++ns) {
    const long col = rowB0 + wn * 64 + ns * 16 + qr;
    const float bv = bias ? bias[col] : 0.f;
#pragma unroll
    for (int ms = 0; ms < 4; ++ms) {
      const long row = rowA0 + wm * 64 + ms * 16 + quad * 4;
#pragma unroll
      for (int r = 0; r < 4; ++r)
        store1(&C[(row + r) * (long)N + col], acc[ms][ns][r] * qs + bv);
    }
  }
}

// ---------------- Causal flash attention v12 ---------------------------------
// Base = v5 (best verified: paired q-tiles {qp,15-qp}, 512 blocks, staged K/V
// via global_load_lds, double-buffered, one barrier/tile, prefetch-ahead,
// swapped QK^T, P slab). ONE graft, device-verified in v9 (round-6, passed):
// softmax denominator via ones-vector MFMA -- li[i] = mfma(pf, ones, li[i])
// accumulates the P row-sums in the SAME D-fragment layout as o, deleting
// the 16-add psum chain + 2 shfl_xor per m-frag and the epilogue shfl.
// Runs on the MFMA pipe (19% busy) instead of VALU (50%, the cap).
// The round-7/8 in-register permlane relayout is ABANDONED: residual 0.082
// absmax traced to an offline-unresolvable lane/packing semantic; slab path
// is verified and its DS cost is already 2-way-alias free.
// Fixed-max softmax; Q pre-scaled by log2e/8 in the Q GEMM -> raw v_exp_f32.
__global__ __launch_bounds__(256) void attn12(
    const u16* __restrict__ Q, const u16* __restrict__ Kg,
    const u16* __restrict__ Vt, u16* __restrict__ ctx) {
  __shared__ __align__(16) u16 KV[2][2][64 * 64];  // [buf][K|V][row*64]
  __shared__ __align__(16) u16 Pl[4][16 * 64];     // [wave][q-row * 64k], XOR-swz

  const int tid = threadIdx.x;
  const int w = tid >> 6, lane = tid & 63;
  const int qr = lane & 15, quad = lane >> 4;
  const int bh = blockIdx.x;
  const int b = bh >> 4, h = bh & 15;

  const long baseQK = ((long)b * S_) * D_ + h * HD_;
  const long baseVt = (long)bh * HD_ * S_;

  // staging map: round t, wave w covers rows t*32+w*8 .. +7; lane -> row +
  // (lane>>3), LDS pos lane&7; global chunk = (lane&7) ^ (row&7) = ^(lane>>3)
  const int sr8 = lane >> 3;
  const int sc8 = ((lane & 7) ^ sr8) * 8;

  bf16x8 vones;
#pragma unroll
  for (int j = 0; j < 8; ++j) vones[j] = (short)0x3F80;  // bf16 1.0

  const int tiles2[2] = {(int)blockIdx.y, 15 - (int)blockIdx.y};

#pragma unroll
  for (int ti = 0; ti < 2; ++ti) {
    const int q0 = tiles2[ti] * 128;
    const int qbase = q0 + w * 32;

    bf16x8 aq[2][2];
#pragma unroll
    for (int i = 0; i < 2; ++i) {
      const u16* qp_ = Q + baseQK + (long)(qbase + i * 16 + qr) * D_;
      aq[i][0] = *(const bf16x8*)(qp_ + quad * 8);
      aq[i][1] = *(const bf16x8*)(qp_ + 32 + quad * 8);
    }

    f32x4 li[2] = {};   // ones-MFMA accumulator: entry r = rowsum(q=quad*4+r)
    f32x4 o[2][4] = {};

    const int nkt = q0 / 64 + 2;  // always even for ti=0 (2*qp+2)

    // prefetch tile 0 into buf 0
#pragma unroll
    for (int t = 0; t < 2; ++t) {
      const int r = t * 32 + w * 8 + sr8;
      glds16(Kg + baseQK + (long)r * D_ + sc8, &KV[0][0][(t * 32 + w * 8) * 64]);
      glds16(Vt + baseVt + (long)r * S_ + sc8, &KV[0][1][(t * 32 + w * 8) * 64]);
    }

    for (int kt = 0; kt < nkt; ++kt) {
      const int kbase = kt * 64;
      const int buf = kt & 1;

      __syncthreads();  // drains vmcnt: KV[buf] ready; KV[buf^1] readers done

      if (kt + 1 < nkt) {  // async prefetch next tile into the other buffer
        const int nb = kbase + 64;
#pragma unroll
        for (int t = 0; t < 2; ++t) {
          const int r = t * 32 + w * 8 + sr8;
          glds16(Kg + baseQK + (long)(nb + r) * D_ + sc8,
                 &KV[buf ^ 1][0][(t * 32 + w * 8) * 64]);
          glds16(Vt + baseVt + (long)r * S_ + nb + sc8,
                 &KV[buf ^ 1][1][(t * 32 + w * 8) * 64]);
        }
      }

      const u16* Ksb = KV[buf][0];
      const u16* Vsb = KV[buf][1];

      // K fragments (A operand of swapped QK^T; shared by both m-frags)
      bf16x8 kf[4][2];
#pragma unroll
      for (int ns = 0; ns < 4; ++ns) {
        const int row = ns * 16 + qr;
        kf[ns][0] = *(const bf16x8*)(&Ksb[row * 64 + ((quad ^ (row & 7)) * 8)]);
        kf[ns][1] =
            *(const bf16x8*)(&Ksb[row * 64 + (((4 + quad) ^ (row & 7)) * 8)]);
      }

      // S^T = K * Q^T: lane holds q = qbase+i*16+qr, k = kbase+ns*16+quad*4+r
      f32x4 s[2][4] = {};
#pragma unroll
      for (int i = 0; i < 2; ++i)
#pragma unroll
        for (int ns = 0; ns < 4; ++ns) {
          s[i][ns] = __builtin_amdgcn_mfma_f32_16x16x32_bf16(
              kf[ns][0], aq[i][0], s[i][ns], 0, 0, 0);
          s[i][ns] = __builtin_amdgcn_mfma_f32_16x16x32_bf16(
              kf[ns][1], aq[i][1], s[i][ns], 0, 0, 0);
        }

      // causal mask (wave-uniform gate per m-frag)
#pragma unroll
      for (int i = 0; i < 2; ++i) {
        if (kbase + 64 > qbase + i * 16) {
          const int qrow = qbase + i * 16 + qr;
#pragma unroll
          for (int ns = 0; ns < 4; ++ns) {
            const int kc = kbase + ns * 16 + quad * 4;
#pragma unroll
            for (int r = 0; r < 4; ++r)
              if (kc + r > qrow) s[i][ns][r] = -1.0e30f;
          }
        }
      }

      // V fragments (B operand of PV; shared by both m-frags)
      bf16x8 vf[4][2];
#pragma unroll
      for (int ns = 0; ns < 4; ++ns) {
        const int row = ns * 16 + qr;
        vf[ns][0] = *(const bf16x8*)(&Vsb[row * 64 + ((quad ^ (row & 7)) * 8)]);
        vf[ns][1] =
            *(const bf16x8*)(&Vsb[row * 64 + (((4 + quad) ^ (row & 7)) * 8)]);
      }

      // fixed-max softmax per-lane + slim P slab (wave-private, in-order DS).
      // P[q][k]: logical 16B chunk k/8 stored at chunk ^ (q&7) within the row.
#pragma unroll
      for (int i = 0; i < 2; ++i) {
#pragma unroll
        for (int ns = 0; ns < 4; ++ns) {
          ushort4 pk;
          pk.x = f2b(fexp2(s[i][ns][0]));
          pk.y = f2b(fexp2(s[i][ns][1]));
          pk.z = f2b(fexp2(s[i][ns][2]));
          pk.w = f2b(fexp2(s[i][ns][3]));
          *(ushort4*)(&Pl[w][qr * 64 +
                             (((2 * ns + (quad >> 1)) ^ (qr & 7)) * 8) +
                             (quad & 1) * 4]) = pk;
        }

        bf16x8 pf0 = *(const bf16x8*)(&Pl[w][qr * 64 + ((quad ^ (qr & 7)) * 8)]);
        bf16x8 pf1 =
            *(const bf16x8*)(&Pl[w][qr * 64 + (((4 + quad) ^ (qr & 7)) * 8)]);
#pragma unroll
        for (int ns = 0; ns < 4; ++ns) {
          o[i][ns] = __builtin_amdgcn_mfma_f32_16x16x32_bf16(pf0, vf[ns][0],
                                                             o[i][ns], 0, 0, 0);
          o[i][ns] = __builtin_amdgcn_mfma_f32_16x16x32_bf16(pf1, vf[ns][1],
                                                             o[i][ns], 0, 0, 0);
        }
        // denominator on the MFMA pipe; D-frag layout matches o (v9-verified)
        li[i] =
            __builtin_amdgcn_mfma_f32_16x16x32_bf16(pf0, vones, li[i], 0, 0, 0);
        li[i] =
            __builtin_amdgcn_mfma_f32_16x16x32_bf16(pf1, vones, li[i], 0, 0, 0);
      }
    }

    // epilogue: li[i][r] is the rowsum for q = qbase+i*16+quad*4+r (no shfl)
#pragma unroll
    for (int i = 0; i < 2; ++i)
#pragma unroll
      for (int r = 0; r < 4; ++r) {
        const float inv = 1.f / li[i][r];
        const long row = qbase + i * 16 + quad * 4 + r;
#pragma unroll
        for (int ns = 0; ns < 4; ++ns)
          ctx[((long)b * S_ + row) * D_ + h * HD_ + ns * 16 + qr] =
              f2b(o[i][ns][r] * inv);
      }
  }
}

// ---------------- launch ------------------------------------------------------
extern "C" void kernel_launch(void* const* d_in, const int* in_sizes, int n_in,
                              void* d_out, int out_size, void* d_ws,
                              size_t ws_size, hipStream_t stream) {
  const float* x  = (const float*)d_in[0];
  const float* Wq = (const float*)d_in[1];
  const float* Wk = (const float*)d_in[2];
  const float* Wv = (const float*)d_in[3];
  const float* Wo = (const float*)d_in[4];
  const float* bo = (const float*)d_in[5];

  u16* ws = (u16*)d_ws;
  u16* xb  = ws;                         // 8.4M elems bf16 x
  u16* Wt  = xb + 8388608l;              // 4 * 1M elems (transposed bf16 W)
  u16* Qb  = Wt + 4l * 1048576;          // Q (pre-scaled), [B,S,H*HD]
  u16* Kb  = Qb + 8388608l;              // K, [B,S,H*HD]
  u16* Vb  = Kb + 8388608l;              // V^T, [B*H, HD, S]
  u16* ctx = Qb;  // alias: 128-row q-tiles are block-exclusive; Q rows are
                  // read (ti loop) before the same rows are written

  // 1) x -> bf16
  cast_x<<<4096, 256, 0, stream>>>(x, xb);

  // 2) transpose+convert the 4 weight matrices
  transpose_w<<<dim3(16, 16, 4), 256, 0, stream>>>(Wq, Wk, Wv, Wo, Wt);

  // 3) QKV projections: Q scaled by log2e/8, V written transposed
  gemm_bt128d<HB><<<dim3(8, 64, 3), 256, 0, stream>>>(
      xb, Wt, 1048576l, (HB*)Qb, 8388608l, nullptr, Vb, 1, 8192, 1024, 1024);

  // 4) causal flash attention -> ctx
  attn12<<<dim3(64, 8), 256, 0, stream>>>(Qb, Kb, Vb, ctx);

  // 5) output projection + bias -> d_out (fp32)
  gemm_bt128d<float><<<dim3(8, 64, 1), 256, 0, stream>>>(
      ctx, Wt + 3l * 1048576, 0, (float*)d_out, 0, bo, nullptr, 0,
      8192, 1024, 1024);
}